// Round 1
// baseline (366.388 us; speedup 1.0000x reference)
//
#include <hip/hip_runtime.h>

#define SEQ 512
#define BATCH 1024
#define NT 64
#define BT (BATCH * NT)  // stride between timesteps in emissions

// ---------------- Kernel A: numerator (tag-path score) ----------------
// One thread per (s, b). Sum over everything via wave-reduce + atomicAdd.
__global__ __launch_bounds__(256) void crf_numer(
    const float* __restrict__ em, const int* __restrict__ tags,
    const int* __restrict__ lens, const float* __restrict__ st,
    const float* __restrict__ en, const float* __restrict__ tr,
    float* __restrict__ out)
{
    int tid = blockIdx.x * 256 + threadIdx.x;   // tid = s*BATCH + b
    int b = tid & (BATCH - 1);
    int s = tid >> 10;
    int L = lens[b];
    int tg = tags[s * BATCH + b];
    float v = 0.f;
    if (s == 0) {
        v = st[tg] + em[(size_t)b * NT + tg];
    } else if (s < L) {
        int tp = tags[(s - 1) * BATCH + b];
        v = tr[tp * NT + tg] + em[(size_t)s * BT + (size_t)b * NT + tg];
    }
    if (s == L - 1) v += en[tg];
    #pragma unroll
    for (int d = 32; d > 0; d >>= 1) v += __shfl_down(v, d);
    if ((threadIdx.x & 63) == 0) atomicAdd(out, v);
}

// ---------------- Kernel B: denominator (forward algorithm) ----------------
// One wave per batch chain. Lane j owns alpha[j] and register column E[0..63][j].
// Per step: p = exp(alpha - alpha0); broadcast p via LDS; dot with E column; log.
__global__ __launch_bounds__(256) void crf_denom(
    const float* __restrict__ em, const int* __restrict__ lens,
    const float* __restrict__ st, const float* __restrict__ en,
    const float* __restrict__ tr, float* __restrict__ out)
{
    __shared__ __align__(16) float p_sh[4][NT];
    const int wv = threadIdx.x >> 6;
    const int lane = threadIdx.x & 63;
    const int b = blockIdx.x * 4 + wv;
    const int L = lens[b];

    // Register-resident E column: e[i] = exp(trans[i][lane])
    float e[NT];
    #pragma unroll
    for (int i = 0; i < NT; ++i) e[i] = __expf(tr[i * NT + lane]);

    const float* emb = em + (size_t)b * NT + lane;
    float alpha = st[lane] + emb[0];

    // 2-deep emission prefetch
    float em_n0 = 0.f, em_n1 = 0.f;
    if (L > 1) em_n0 = emb[(size_t)1 * BT];
    if (L > 2) em_n1 = emb[(size_t)2 * BT];

    for (int s = 1; s < L; ++s) {
        float emv = em_n0;
        em_n0 = em_n1;
        if (s + 2 < L) em_n1 = emb[(size_t)(s + 2) * BT];

        float m = __shfl(alpha, 0);            // cheap shift (lane-0 alpha)
        float p = __expf(alpha - m);
        p_sh[wv][lane] = p;
        asm volatile("s_waitcnt lgkmcnt(0)" ::: "memory");  // write visible wave-wide

        float d0 = 0.f, d1 = 0.f, d2 = 0.f, d3 = 0.f;
        float d4 = 0.f, d5 = 0.f, d6 = 0.f, d7 = 0.f;
        const float4* pv = reinterpret_cast<const float4*>(p_sh[wv]);
        #pragma unroll
        for (int i = 0; i < NT; i += 8) {
            float4 a = pv[i / 4];              // same-addr broadcast ds_read_b128
            float4 c = pv[i / 4 + 1];
            d0 = fmaf(a.x, e[i + 0], d0);
            d1 = fmaf(a.y, e[i + 1], d1);
            d2 = fmaf(a.z, e[i + 2], d2);
            d3 = fmaf(a.w, e[i + 3], d3);
            d4 = fmaf(c.x, e[i + 4], d4);
            d5 = fmaf(c.y, e[i + 5], d5);
            d6 = fmaf(c.z, e[i + 6], d6);
            d7 = fmaf(c.w, e[i + 7], d7);
        }
        float dot = ((d0 + d1) + (d2 + d3)) + ((d4 + d5) + (d6 + d7));
        alpha = emv + m + __logf(dot);
    }

    // denom_b = logsumexp_j(alpha_j + end_j); subtract from output
    float x = alpha + en[lane];
    float mx = x;
    #pragma unroll
    for (int d = 32; d > 0; d >>= 1) mx = fmaxf(mx, __shfl_xor(mx, d));
    float sume = __expf(x - mx);
    #pragma unroll
    for (int d = 32; d > 0; d >>= 1) sume += __shfl_xor(sume, d);
    if (lane == 0) atomicAdd(out, -(mx + __logf(sume)));
}

extern "C" void kernel_launch(void* const* d_in, const int* in_sizes, int n_in,
                              void* d_out, int out_size, void* d_ws, size_t ws_size,
                              hipStream_t stream)
{
    const float* emissions = (const float*)d_in[0];
    const int*   tags      = (const int*)d_in[1];
    const int*   lengths   = (const int*)d_in[2];
    const float* start_tr  = (const float*)d_in[3];
    const float* end_tr    = (const float*)d_in[4];
    const float* trans     = (const float*)d_in[5];
    float* out = (float*)d_out;

    hipMemsetAsync(out, 0, sizeof(float), stream);

    // Denominator: 1024 waves, one per batch chain (long-running) — launch first.
    crf_denom<<<BATCH / 4, 256, 0, stream>>>(emissions, lengths, start_tr, end_tr,
                                             trans, out);
    // Numerator: one thread per (s, b).
    crf_numer<<<(SEQ * BATCH) / 256, 256, 0, stream>>>(emissions, tags, lengths,
                                                       start_tr, end_tr, trans, out);
}

// Round 2
// 185.781 us; speedup vs baseline: 1.9721x; 1.9721x over previous
//
#include <hip/hip_runtime.h>

#define SEQ 512
#define BATCH 1024
#define NT 64
#define BT (BATCH * NT)        // stride between timesteps in emissions
#define NUMER_BLOCKS 512
#define LN2F 0.69314718055994531f

// Fused kernel: blocks [0, BATCH) run the forward-algorithm denominator (one
// wave per chain, linear-domain with power-of-2 rescaling -> no exp/log on the
// critical path). Blocks [BATCH, BATCH+NUMER_BLOCKS) accumulate the tag-path
// numerator (grid-stride gather). Both atomicAdd into the single scalar out.
__global__ __launch_bounds__(64, 1) void crf_fused(
    const float* __restrict__ em, const int* __restrict__ tags,
    const int* __restrict__ lens, const float* __restrict__ st,
    const float* __restrict__ en, const float* __restrict__ tr,
    float* __restrict__ out)
{
    __shared__ __align__(16) float p_sh[NT];
    const int lane = threadIdx.x;   // block = 1 wave

    if (blockIdx.x < BATCH) {
        // ---------------- denominator: one wave per batch chain ----------------
        const int b = blockIdx.x;
        const int L = lens[b];

        // Register-resident E column: e[i] = exp(trans[i][lane])
        float e[NT];
        #pragma unroll
        for (int i = 0; i < NT; ++i) e[i] = __expf(tr[i * NT + lane]);

        const float* emb = em + (size_t)b * NT + lane;

        // init: alpha0_j = st_j + em0_j ; p_j = exp(alpha0_j - alpha0_0)
        float x0 = st[lane] + emb[0];
        float xs = __uint_as_float(__builtin_amdgcn_readfirstlane(__float_as_uint(x0)));
        float p = __expf(x0 - xs);
        int ksum = 0;

        // 2-deep emission prefetch
        float em_n0 = 0.f, em_n1 = 0.f;
        if (L > 1) em_n0 = emb[(size_t)1 * BT];
        if (L > 2) em_n1 = emb[(size_t)2 * BT];

        for (int s = 1; s < L; ++s) {
            p_sh[lane] = p;
            float eexp = __expf(em_n0);            // exp of this step's emission
            em_n0 = em_n1;
            if (s + 2 < L) em_n1 = emb[(size_t)(s + 2) * BT];
            asm volatile("s_waitcnt lgkmcnt(0)" ::: "memory");

            float d0 = 0.f, d1 = 0.f, d2 = 0.f, d3 = 0.f;
            float d4 = 0.f, d5 = 0.f, d6 = 0.f, d7 = 0.f;
            const float4* pv = reinterpret_cast<const float4*>(p_sh);
            #pragma unroll
            for (int i = 0; i < NT; i += 8) {
                float4 a = pv[i / 4];              // same-addr broadcast ds_read_b128
                float4 c = pv[i / 4 + 1];
                d0 = fmaf(a.x, e[i + 0], d0);
                d1 = fmaf(a.y, e[i + 1], d1);
                d2 = fmaf(a.z, e[i + 2], d2);
                d3 = fmaf(a.w, e[i + 3], d3);
                d4 = fmaf(c.x, e[i + 4], d4);
                d5 = fmaf(c.y, e[i + 5], d5);
                d6 = fmaf(c.z, e[i + 6], d6);
                d7 = fmaf(c.w, e[i + 7], d7);
            }
            float dot = ((d0 + d1) + (d2 + d3)) + ((d4 + d5) + (d6 + d7));
            float pj = dot * eexp;                 // p' (linear domain, > 0)

            // rescale by 2^-k, k = exponent of lane-0's p' (no log on crit path)
            unsigned b0 = __builtin_amdgcn_readfirstlane(__float_as_uint(pj));
            int k = (int)(b0 >> 23) - 127;         // positive float -> sign bit 0
            ksum += k;
            float scale = __uint_as_float((unsigned)(127 - k) << 23);  // 2^-k
            p = pj * scale;
        }

        // denom_b = xs + ksum*ln2 + log( sum_j p_j * exp(end_j) )
        float term = p * __expf(en[lane]);
        #pragma unroll
        for (int d = 32; d > 0; d >>= 1) term += __shfl_xor(term, d);
        if (lane == 0)
            atomicAdd(out, -(xs + (float)ksum * LN2F + __logf(term)));
    } else {
        // ---------------- numerator: tag-path score (grid-stride gather) -------
        const int t0 = (blockIdx.x - BATCH) * 64 + lane;
        float acc = 0.f;
        for (int idx = t0; idx < SEQ * BATCH; idx += NUMER_BLOCKS * 64) {
            int b = idx & (BATCH - 1);
            int s = idx >> 10;
            int L = lens[b];
            int tg = tags[s * BATCH + b];
            float v = 0.f;
            if (s == 0) {
                v = st[tg] + em[(size_t)b * NT + tg];
            } else if (s < L) {
                int tp = tags[(s - 1) * BATCH + b];
                v = tr[tp * NT + tg] + em[(size_t)s * BT + (size_t)b * NT + tg];
            }
            if (s == L - 1) v += en[tg];
            acc += v;
        }
        #pragma unroll
        for (int d = 32; d > 0; d >>= 1) acc += __shfl_xor(acc, d);
        if (lane == 0) atomicAdd(out, acc);
    }
}

extern "C" void kernel_launch(void* const* d_in, const int* in_sizes, int n_in,
                              void* d_out, int out_size, void* d_ws, size_t ws_size,
                              hipStream_t stream)
{
    const float* emissions = (const float*)d_in[0];
    const int*   tags      = (const int*)d_in[1];
    const int*   lengths   = (const int*)d_in[2];
    const float* start_tr  = (const float*)d_in[3];
    const float* end_tr    = (const float*)d_in[4];
    const float* trans     = (const float*)d_in[5];
    float* out = (float*)d_out;

    hipMemsetAsync(out, 0, sizeof(float), stream);

    crf_fused<<<BATCH + NUMER_BLOCKS, 64, 0, stream>>>(
        emissions, tags, lengths, start_tr, end_tr, trans, out);
}